// Round 1
// baseline (3891.779 us; speedup 1.0000x reference)
//
#include <hip/hip_runtime.h>

#define EPS 1e-5f
#define NRED 65536.0f   // B*H*W = 64*32*32

// ---------------- stats workspace layout (floats, at st base) ----------------
// [0,64)      sum1        (zeroed per nor_conv)
// [64,128)    sumsq1      (zeroed)
// [128,640)   sum2[k][c]  (zeroed)
// [640,1152)  sumsq2[k][c](zeroed)
// [1152,1216) s1[c]   = r1*m1
// [1216,1280) b1[c]   = -mu1*r1*m1
// [1280,1792) g[j][c] = sum_{k>=j} a2[k]*r2[k][c]
// [1792,1856) bias2[c]= -sum_k a2[k]*mu2[k][c]*r2[k][c]
// [1856,1920) cm[c]   = m1[c]*m2[c]

__global__ void prep_cm_k(const float* __restrict__ a1, const float* __restrict__ a2,
                          float* __restrict__ st) {
  int c = threadIdx.x;  // 64
  int g = c >> 3;
  float m1 = 0.f, m2 = 0.f;
  for (int i = g; i < 8; ++i) { m1 += a1[i]; m2 += a2[i]; }
  st[1856 + c] = m1 * m2;
}

__global__ void finalizeA_k(const float* __restrict__ a1, float* __restrict__ st) {
  int c = threadIdx.x;  // 64
  int g = c >> 3;
  float m = 0.f;
  for (int i = g; i < 8; ++i) m += a1[i];
  float mu = st[c] / NRED;
  float var = st[64 + c] / NRED - mu * mu;
  float r = rsqrtf(var + EPS);
  st[1152 + c] = r * m;
  st[1216 + c] = -mu * r * m;
}

__global__ void finalizeC_k(const float* __restrict__ a2, float* __restrict__ st) {
  int c = threadIdx.x;  // 64
  float r2[8], mu2[8];
  for (int k = 0; k < 8; ++k) {
    float mu = st[128 + k * 64 + c] / NRED;
    float var = st[640 + k * 64 + c] / NRED - mu * mu;
    mu2[k] = mu;
    r2[k] = rsqrtf(var + EPS);
  }
  float bias = 0.f;
  for (int k = 0; k < 8; ++k) bias -= a2[k] * mu2[k] * r2[k];
  st[1792 + c] = bias;
  float suf = 0.f;
  for (int j = 7; j >= 0; --j) { suf += a2[j] * r2[j]; st[1280 + j * 64 + c] = suf; }
}

// ---------------- conv1: t = conv3x3(relu(x), w1) ----------------
// block 128 = 8 rows x 16 col-pairs; grid (4 rowTiles, 2 coTiles, 64 B)
__global__ __launch_bounds__(128) void convA_k(const float* __restrict__ x,
                                               const float* __restrict__ w,
                                               float* __restrict__ t) {
  __shared__ float wsh[2304];  // [cis 8][co 32][tap 9]
  const int tid = threadIdx.x;
  const int col0 = (tid & 15) * 2;
  const int h = blockIdx.x * 8 + (tid >> 4);
  const int coT = blockIdx.y;
  const int b = blockIdx.z;
  float acc[32][2];
#pragma unroll
  for (int i = 0; i < 32; ++i) { acc[i][0] = 0.f; acc[i][1] = 0.f; }
  const float* xb = x + (size_t)b * 65536;
  for (int cig = 0; cig < 8; ++cig) {
    __syncthreads();
    for (int idx = tid; idx < 2304; idx += 128) {
      int cis = idx / 288;
      int rem = idx - cis * 288;
      int co = rem / 9;
      int tap = rem - co * 9;
      wsh[idx] = w[((coT * 32 + co) * 64 + cig * 8 + cis) * 9 + tap];
    }
    __syncthreads();
#pragma unroll 1
    for (int cis = 0; cis < 8; ++cis) {
      const float* xp = xb + (cig * 8 + cis) * 1024;
      float xv[3][4];
#pragma unroll
      for (int dy = 0; dy < 3; ++dy) {
        int y = h + dy - 1;
        bool yv = (unsigned)y < 32u;
#pragma unroll
        for (int j = 0; j < 4; ++j) {
          int xc = col0 - 1 + j;
          bool v = yv && ((unsigned)xc < 32u);
          float val = v ? xp[y * 32 + xc] : 0.f;
          xv[dy][j] = fmaxf(val, 0.f);  // relu
        }
      }
      const float* wl = &wsh[cis * 288];
#pragma unroll
      for (int co = 0; co < 32; ++co) {
        float a0 = acc[co][0], a1v = acc[co][1];
#pragma unroll
        for (int dy = 0; dy < 3; ++dy)
#pragma unroll
          for (int dx = 0; dx < 3; ++dx) {
            float wv = wl[co * 9 + dy * 3 + dx];
            a0 = fmaf(xv[dy][dx], wv, a0);
            a1v = fmaf(xv[dy][dx + 1], wv, a1v);
          }
        acc[co][0] = a0; acc[co][1] = a1v;
      }
    }
  }
  float* tp = t + (size_t)b * 65536 + h * 32 + col0;
#pragma unroll
  for (int co = 0; co < 32; ++co) {
    float2 v2 = make_float2(acc[co][0], acc[co][1]);
    *(float2*)&tp[(size_t)(coT * 32 + co) * 1024] = v2;
  }
}

// ---------------- per-channel mean/var of t ----------------
__global__ __launch_bounds__(256) void statsA_k(const float* __restrict__ t,
                                                float* __restrict__ st) {
  int c = blockIdx.x, chunk = blockIdx.y;  // 64 x 8
  float s = 0.f, q = 0.f;
  for (int b = chunk * 8; b < chunk * 8 + 8; ++b) {
    const float* p = t + ((size_t)b * 64 + c) * 1024;
    for (int i = threadIdx.x; i < 1024; i += 256) {
      float v = p[i];
      s += v; q += v * v;
    }
  }
#pragma unroll
  for (int off = 32; off; off >>= 1) { s += __shfl_xor(s, off); q += __shfl_xor(q, off); }
  __shared__ float ls[8];
  int wid = threadIdx.x >> 6, lane = threadIdx.x & 63;
  if (lane == 0) { ls[wid] = s; ls[4 + wid] = q; }
  __syncthreads();
  if (threadIdx.x == 0) {
    atomicAdd(&st[c], ls[0] + ls[1] + ls[2] + ls[3]);
    atomicAdd(&st[64 + c], ls[4] + ls[5] + ls[6] + ls[7]);
  }
}

// ---------------- conv2 shared body: per-group accumulators ----------------
__device__ __forceinline__ void stage_w2(const float* __restrict__ w2, int coT,
                                         float* __restrict__ wsh, int tid) {
  for (int idx = tid; idx < 2304; idx += 128) {  // [ci 64][cs 4][tap 9]
    int ci = idx / 36;
    int rem = idx - ci * 36;
    int cs = rem / 9;
    int tap = rem - cs * 9;
    wsh[idx] = w2[((coT * 4 + cs) * 64 + ci) * 9 + tap];
  }
  __syncthreads();
}

__device__ __forceinline__ void conv2_body(const float* __restrict__ tb,
                                           const float* __restrict__ st,
                                           const float* __restrict__ wsh,
                                           int h, int col0, float acc[4][8][2]) {
#pragma unroll
  for (int cs = 0; cs < 4; ++cs)
#pragma unroll
    for (int g = 0; g < 8; ++g) { acc[cs][g][0] = 0.f; acc[cs][g][1] = 0.f; }
#pragma unroll
  for (int g = 0; g < 8; ++g) {
#pragma unroll 1
    for (int cis = 0; cis < 8; ++cis) {
      int ci = g * 8 + cis;
      float sc = st[1152 + ci];  // uniform -> scalar load
      float bc = st[1216 + ci];
      const float* xp = tb + ci * 1024;
      float xv[3][4];
#pragma unroll
      for (int dy = 0; dy < 3; ++dy) {
        int y = h + dy - 1;
        bool yv = (unsigned)y < 32u;
#pragma unroll
        for (int j = 0; j < 4; ++j) {
          int xc = col0 - 1 + j;
          bool v = yv && ((unsigned)xc < 32u);
          xv[dy][j] = v ? fmaf(xp[y * 32 + xc], sc, bc) : 0.f;  // h = t*s1+b1
        }
      }
      const float* wl = &wsh[ci * 36];
#pragma unroll
      for (int cs = 0; cs < 4; ++cs) {
        float a0 = acc[cs][g][0], a1v = acc[cs][g][1];
#pragma unroll
        for (int dy = 0; dy < 3; ++dy)
#pragma unroll
          for (int dx = 0; dx < 3; ++dx) {
            float wv = wl[cs * 9 + dy * 3 + dx];
            a0 = fmaf(xv[dy][dx], wv, a0);
            a1v = fmaf(xv[dy][dx + 1], wv, a1v);
          }
        acc[cs][g][0] = a0; acc[cs][g][1] = a1v;
      }
    }
  }
}

// ---------------- conv2 stats pass: sum/sumsq of prefix P_k per (k,c) ----------------
// block 128; grid (4 rowTiles, 16 coTiles, 64 B)
__global__ __launch_bounds__(128) void convC_k(const float* __restrict__ t,
                                               float* __restrict__ st,
                                               const float* __restrict__ w2) {
  __shared__ float wsh[2304];
  __shared__ float red[2][64];
  const int tid = threadIdx.x;
  const int col0 = (tid & 15) * 2;
  const int h = blockIdx.x * 8 + (tid >> 4);
  const int coT = blockIdx.y;
  const int b = blockIdx.z;
  stage_w2(w2, coT, wsh, tid);
  float acc[4][8][2];
  conv2_body(t + (size_t)b * 65536, st, wsh, h, col0, acc);
  const int lane = tid & 63, wid = tid >> 6;
#pragma unroll
  for (int cs = 0; cs < 4; ++cs) {
    float p0 = 0.f, p1 = 0.f;
#pragma unroll
    for (int k = 0; k < 8; ++k) {
      p0 += acc[cs][k][0];
      p1 += acc[cs][k][1];
      float ps = p0 + p1;
      float qs = p0 * p0 + p1 * p1;
#pragma unroll
      for (int off = 32; off; off >>= 1) {
        ps += __shfl_xor(ps, off);
        qs += __shfl_xor(qs, off);
      }
      if (lane == 0) { red[wid][cs * 16 + k * 2] = ps; red[wid][cs * 16 + k * 2 + 1] = qs; }
    }
  }
  __syncthreads();
  if (tid < 64) {
    float v = red[0][tid] + red[1][tid];
    int cs = tid >> 4;
    int k = (tid >> 1) & 7;
    int isq = tid & 1;
    atomicAdd(&st[(isq ? 640 : 128) + k * 64 + coT * 4 + cs], v);
  }
}

// ---------------- conv2 output pass + fused epilogue ----------------
// MODE 0: write n1 | 1: write n2 = v + avgpool3(n1)*cm | 2: out = v + inputs*cm | 3: out += v
template <int MODE>
__global__ __launch_bounds__(128) void convE_k(const float* __restrict__ t,
                                               const float* __restrict__ st,
                                               const float* __restrict__ w2,
                                               float* __restrict__ outp,
                                               const float* __restrict__ aux) {
  __shared__ float wsh[2304];
  const int tid = threadIdx.x;
  const int col0 = (tid & 15) * 2;
  const int h = blockIdx.x * 8 + (tid >> 4);
  const int coT = blockIdx.y;
  const int b = blockIdx.z;
  stage_w2(w2, coT, wsh, tid);
  float acc[4][8][2];
  conv2_body(t + (size_t)b * 65536, st, wsh, h, col0, acc);
#pragma unroll
  for (int cs = 0; cs < 4; ++cs) {
    int c = coT * 4 + cs;
    float bias = st[1792 + c];
    float v0 = bias, v1 = bias;
#pragma unroll
    for (int j = 0; j < 8; ++j) {
      float gj = st[1280 + j * 64 + c];
      v0 = fmaf(gj, acc[cs][j][0], v0);
      v1 = fmaf(gj, acc[cs][j][1], v1);
    }
    size_t base = (size_t)b * 65536 + (size_t)c * 1024 + h * 32 + col0;
    if (MODE == 0) {
      outp[base] = v0; outp[base + 1] = v1;
    } else if (MODE == 1) {
      float cmv = st[1856 + c];
      const float* np_ = aux + (size_t)b * 65536 + (size_t)c * 1024;
      int y0 = h > 0 ? h - 1 : 0, y1 = h < 31 ? h + 1 : 31;
      float s0 = 0.f, s1 = 0.f;
      for (int y = y0; y <= y1; ++y) {
        float r[4];
#pragma unroll
        for (int j = 0; j < 4; ++j) {
          int xc = col0 - 1 + j;
          r[j] = ((unsigned)xc < 32u) ? np_[y * 32 + xc] : 0.f;
        }
        s0 += r[0] + r[1] + r[2];
        s1 += r[1] + r[2] + r[3];
      }
      float ny = (float)(y1 - y0 + 1);
      float d0 = ny * (col0 == 0 ? 2.f : 3.f);
      float d1 = ny * (col0 + 1 == 31 ? 2.f : 3.f);
      outp[base] = v0 + (s0 / d0) * cmv;
      outp[base + 1] = v1 + (s1 / d1) * cmv;
    } else if (MODE == 2) {
      float cmv = st[1856 + c];
      outp[base] = v0 + aux[base] * cmv;
      outp[base + 1] = v1 + aux[base + 1] * cmv;
    } else {
      outp[base] += v0;
      outp[base + 1] += v1;
    }
  }
}

extern "C" void kernel_launch(void* const* d_in, const int* in_sizes, int n_in,
                              void* d_out, int out_size, void* d_ws, size_t ws_size,
                              hipStream_t stream) {
  const float* x  = (const float*)d_in[0];
  const float* a1 = (const float*)d_in[1];
  const float* a2 = (const float*)d_in[2];
  const float* W1[4] = {(const float*)d_in[3], (const float*)d_in[5],
                        (const float*)d_in[7], (const float*)d_in[9]};
  const float* W2[4] = {(const float*)d_in[4], (const float*)d_in[6],
                        (const float*)d_in[8], (const float*)d_in[10]};
  float* out = (float*)d_out;
  float* wsf = (float*)d_ws;
  float* n1 = wsf;                 // 16 MB
  float* n2 = wsf + 4194304;       // 16 MB
  float* t  = wsf + 8388608;       // 16 MB
  float* st = wsf + 12582912;      // stats/coeffs (~7.5 KB)

  prep_cm_k<<<1, 64, 0, stream>>>(a1, a2, st);

  dim3 gA(4, 2, 64), gC(4, 16, 64);

  auto norconv = [&](const float* xin, const float* w1, const float* w2) {
    hipMemsetAsync(st, 0, 1152 * sizeof(float), stream);
    convA_k<<<gA, 128, 0, stream>>>(xin, w1, t);
    statsA_k<<<dim3(64, 8), 256, 0, stream>>>(t, st);
    finalizeA_k<<<1, 64, 0, stream>>>(a1, st);
    convC_k<<<gC, 128, 0, stream>>>(t, st, w2);
    finalizeC_k<<<1, 64, 0, stream>>>(a2, st);
  };

  // n1 = nor_conv(inputs, W1_0, W2_0)
  norconv(x, W1[0], W2[0]);
  convE_k<0><<<gC, 128, 0, stream>>>(t, st, W2[0], n1, nullptr);
  // n2 = nor_conv(inputs, W1_1, W2_1) + avgpool3(n1)*cm
  norconv(x, W1[1], W2[1]);
  convE_k<1><<<gC, 128, 0, stream>>>(t, st, W2[1], n2, n1);
  // out = inputs*cm + nor_conv(n1, W1_4, W2_4)
  norconv(n1, W1[2], W2[2]);
  convE_k<2><<<gC, 128, 0, stream>>>(t, st, W2[2], out, x);
  // out += nor_conv(n2, W1_5, W2_5)
  norconv(n2, W1[3], W2[3]);
  convE_k<3><<<gC, 128, 0, stream>>>(t, st, W2[3], out, nullptr);
}

// Round 2
// 3787.827 us; speedup vs baseline: 1.0274x; 1.0274x over previous
//
#include <hip/hip_runtime.h>

#define EPS 1e-5f
#define NRED 65536.0f   // B*H*W = 64*32*32

// ---------------- stats workspace layout (floats, at st base) ----------------
// [0,64)      sum1        (zeroed per nor_conv)
// [64,128)    sumsq1      (zeroed)
// [128,640)   sum2[k][c]  (zeroed)
// [640,1152)  sumsq2[k][c](zeroed)
// [1152,1216) s1[c]   = r1*m1
// [1216,1280) b1[c]   = -mu1*r1*m1
// [1280,1792) g[j][c] = sum_{k>=j} a2[k]*r2[k][c]
// [1792,1856) bias2[c]= -sum_k a2[k]*mu2[k][c]*r2[k][c]
// [1856,1920) cm[c]   = m1[c]*m2[c]

__global__ void prep_cm_k(const float* __restrict__ a1, const float* __restrict__ a2,
                          float* __restrict__ st) {
  int c = threadIdx.x;  // 64
  int g = c >> 3;
  float m1 = 0.f, m2 = 0.f;
  for (int i = g; i < 8; ++i) { m1 += a1[i]; m2 += a2[i]; }
  st[1856 + c] = m1 * m2;
}

__global__ void finalizeA_k(const float* __restrict__ a1, float* __restrict__ st) {
  int c = threadIdx.x;  // 64
  int g = c >> 3;
  float m = 0.f;
  for (int i = g; i < 8; ++i) m += a1[i];
  float mu = st[c] / NRED;
  float var = st[64 + c] / NRED - mu * mu;
  float r = rsqrtf(var + EPS);
  st[1152 + c] = r * m;
  st[1216 + c] = -mu * r * m;
}

__global__ void finalizeC_k(const float* __restrict__ a2, float* __restrict__ st) {
  int c = threadIdx.x;  // 64
  float r2[8], mu2[8];
  for (int k = 0; k < 8; ++k) {
    float mu = st[128 + k * 64 + c] / NRED;
    float var = st[640 + k * 64 + c] / NRED - mu * mu;
    mu2[k] = mu;
    r2[k] = rsqrtf(var + EPS);
  }
  float bias = 0.f;
  for (int k = 0; k < 8; ++k) bias -= a2[k] * mu2[k] * r2[k];
  st[1792 + c] = bias;
  float suf = 0.f;
  for (int j = 7; j >= 0; --j) { suf += a2[j] * r2[j]; st[1280 + j * 64 + c] = suf; }
}

// prepE: fold g[j,co] into conv2 weights -> wE[ci][co][tap], so convE has no
// group dimension. grid(64=co), block(64=ci).
__global__ void prepE_k(const float* __restrict__ w2, const float* __restrict__ st,
                        float* __restrict__ wE) {
  int co = blockIdx.x;
  int ci = threadIdx.x;
  float g = st[1280 + (ci >> 3) * 64 + co];
  const float* src = w2 + (size_t)(co * 64 + ci) * 9;
  float* dst = wE + (size_t)(ci * 64 + co) * 9;
#pragma unroll
  for (int tp = 0; tp < 9; ++tp) dst[tp] = src[tp] * g;
}

// ---------------- conv1: t = conv3x3(relu(x), w1) + fused per-channel stats ----
// block 128 = 8 rows x 16 col-pairs; grid (4 rowTiles, 4 coTiles(16co), 64 B)
// Weights read via wave-uniform (scalar) loads -- no LDS staging.
__global__ __launch_bounds__(128) void convA_k(const float* __restrict__ x,
                                               const float* __restrict__ w,
                                               float* __restrict__ t,
                                               float* __restrict__ st) {
  const int tid = threadIdx.x;
  const int col0 = (tid & 15) * 2;
  const int h = blockIdx.x * 8 + (tid >> 4);
  const int coT = blockIdx.y;
  const int b = blockIdx.z;
  float acc[16][2];
#pragma unroll
  for (int i = 0; i < 16; ++i) { acc[i][0] = 0.f; acc[i][1] = 0.f; }
  const float* xb = x + (size_t)b * 65536;
#pragma unroll 1
  for (int ci = 0; ci < 64; ++ci) {
    const float* xp = xb + ci * 1024;
    float xv[3][4];
#pragma unroll
    for (int dy = 0; dy < 3; ++dy) {
      int y = h + dy - 1;
      bool yv = (unsigned)y < 32u;
#pragma unroll
      for (int j = 0; j < 4; ++j) {
        int xc = col0 - 1 + j;
        bool v = yv && ((unsigned)xc < 32u);
        float val = v ? xp[y * 32 + xc] : 0.f;
        xv[dy][j] = fmaxf(val, 0.f);  // relu
      }
    }
#pragma unroll
    for (int co = 0; co < 16; ++co) {
      const float* wl = w + (size_t)((coT * 16 + co) * 64 + ci) * 9;  // uniform -> s_load
      float a0 = acc[co][0], a1v = acc[co][1];
#pragma unroll
      for (int dy = 0; dy < 3; ++dy)
#pragma unroll
        for (int dx = 0; dx < 3; ++dx) {
          float wv = wl[dy * 3 + dx];
          a0 = fmaf(xv[dy][dx], wv, a0);
          a1v = fmaf(xv[dy][dx + 1], wv, a1v);
        }
      acc[co][0] = a0; acc[co][1] = a1v;
    }
  }
  float* tp = t + (size_t)b * 65536 + (size_t)(coT * 16) * 1024 + h * 32 + col0;
#pragma unroll
  for (int co = 0; co < 16; ++co) {
    float2 v2 = make_float2(acc[co][0], acc[co][1]);
    *(float2*)&tp[(size_t)co * 1024] = v2;
  }
  // fused per-channel sum / sumsq (over this block's 256 pixels)
  __shared__ float sred[2][16], qred[2][16];
  const int lane = tid & 63, wid = tid >> 6;
#pragma unroll
  for (int co = 0; co < 16; ++co) {
    float s = acc[co][0] + acc[co][1];
    float q = acc[co][0] * acc[co][0] + acc[co][1] * acc[co][1];
#pragma unroll
    for (int off = 32; off; off >>= 1) { s += __shfl_xor(s, off); q += __shfl_xor(q, off); }
    if (lane == 0) { sred[wid][co] = s; qred[wid][co] = q; }
  }
  __syncthreads();
  if (tid < 16) {
    atomicAdd(&st[coT * 16 + tid], sred[0][tid] + sred[1][tid]);
  } else if (tid < 32) {
    int c = tid - 16;
    atomicAdd(&st[64 + coT * 16 + c], qred[0][c] + qred[1][c]);
  }
}

// ---------------- conv2 stats pass: sum/sumsq of prefix P_k per (k,c) ----------------
// block 128; grid (4 rowTiles, 16 coTiles(4co), 64 B). Scalar-load weights.
__global__ __launch_bounds__(128) void convC_k(const float* __restrict__ t,
                                               float* __restrict__ st,
                                               const float* __restrict__ w2) {
  __shared__ float red[2][64];
  const int tid = threadIdx.x;
  const int col0 = (tid & 15) * 2;
  const int h = blockIdx.x * 8 + (tid >> 4);
  const int coT = blockIdx.y;
  const int b = blockIdx.z;
  const float* tb = t + (size_t)b * 65536;
  float acc[4][8][2];
#pragma unroll
  for (int cs = 0; cs < 4; ++cs)
#pragma unroll
    for (int g = 0; g < 8; ++g) { acc[cs][g][0] = 0.f; acc[cs][g][1] = 0.f; }
#pragma unroll 1
  for (int ci = 0; ci < 64; ++ci) {
    int g = ci >> 3;
    float sc = st[1152 + ci];
    float bc = st[1216 + ci];
    const float* xp = tb + ci * 1024;
    float xv[3][4];
#pragma unroll
    for (int dy = 0; dy < 3; ++dy) {
      int y = h + dy - 1;
      bool yv = (unsigned)y < 32u;
#pragma unroll
      for (int j = 0; j < 4; ++j) {
        int xc = col0 - 1 + j;
        bool v = yv && ((unsigned)xc < 32u);
        xv[dy][j] = v ? fmaf(xp[y * 32 + xc], sc, bc) : 0.f;  // h = t*s1+b1
      }
    }
#pragma unroll
    for (int cs = 0; cs < 4; ++cs) {
      const float* wl = w2 + (size_t)((coT * 4 + cs) * 64 + ci) * 9;  // uniform
      float a0 = acc[cs][g][0], a1v = acc[cs][g][1];
#pragma unroll
      for (int dy = 0; dy < 3; ++dy)
#pragma unroll
        for (int dx = 0; dx < 3; ++dx) {
          float wv = wl[dy * 3 + dx];
          a0 = fmaf(xv[dy][dx], wv, a0);
          a1v = fmaf(xv[dy][dx + 1], wv, a1v);
        }
      acc[cs][g][0] = a0; acc[cs][g][1] = a1v;
    }
  }
  const int lane = tid & 63, wid = tid >> 6;
#pragma unroll
  for (int cs = 0; cs < 4; ++cs) {
    float p0 = 0.f, p1 = 0.f;
#pragma unroll
    for (int k = 0; k < 8; ++k) {
      p0 += acc[cs][k][0];
      p1 += acc[cs][k][1];
      float ps = p0 + p1;
      float qs = p0 * p0 + p1 * p1;
#pragma unroll
      for (int off = 32; off; off >>= 1) {
        ps += __shfl_xor(ps, off);
        qs += __shfl_xor(qs, off);
      }
      if (lane == 0) { red[wid][cs * 16 + k * 2] = ps; red[wid][cs * 16 + k * 2 + 1] = qs; }
    }
  }
  __syncthreads();
  if (tid < 64) {
    float v = red[0][tid] + red[1][tid];
    int cs = tid >> 4;
    int k = (tid >> 1) & 7;
    int isq = tid & 1;
    atomicAdd(&st[(isq ? 640 : 128) + k * 64 + coT * 4 + cs], v);
  }
}

// ---------------- conv2 output pass (g folded into wE) + fused epilogue -------
// block 128; grid (4 rowTiles, 4 coTiles(16co), 64 B)
// MODE 0: write n1 | 1: write n2 = v + avgpool3(n1)*cm | 2: out = v + inputs*cm | 3: out += v
template <int MODE>
__global__ __launch_bounds__(128) void convE_k(const float* __restrict__ t,
                                               const float* __restrict__ st,
                                               const float* __restrict__ wE,
                                               float* __restrict__ outp,
                                               const float* __restrict__ aux) {
  const int tid = threadIdx.x;
  const int col0 = (tid & 15) * 2;
  const int h = blockIdx.x * 8 + (tid >> 4);
  const int coT = blockIdx.y;
  const int b = blockIdx.z;
  const float* tb = t + (size_t)b * 65536;
  float acc[16][2];
#pragma unroll
  for (int i = 0; i < 16; ++i) { acc[i][0] = 0.f; acc[i][1] = 0.f; }
#pragma unroll 1
  for (int ci = 0; ci < 64; ++ci) {
    float sc = st[1152 + ci];
    float bc = st[1216 + ci];
    const float* xp = tb + ci * 1024;
    float xv[3][4];
#pragma unroll
    for (int dy = 0; dy < 3; ++dy) {
      int y = h + dy - 1;
      bool yv = (unsigned)y < 32u;
#pragma unroll
      for (int j = 0; j < 4; ++j) {
        int xc = col0 - 1 + j;
        bool v = yv && ((unsigned)xc < 32u);
        xv[dy][j] = v ? fmaf(xp[y * 32 + xc], sc, bc) : 0.f;
      }
    }
#pragma unroll
    for (int co = 0; co < 16; ++co) {
      const float* wl = wE + (size_t)(ci * 64 + coT * 16 + co) * 9;  // uniform
      float a0 = acc[co][0], a1v = acc[co][1];
#pragma unroll
      for (int dy = 0; dy < 3; ++dy)
#pragma unroll
        for (int dx = 0; dx < 3; ++dx) {
          float wv = wl[dy * 3 + dx];
          a0 = fmaf(xv[dy][dx], wv, a0);
          a1v = fmaf(xv[dy][dx + 1], wv, a1v);
        }
      acc[co][0] = a0; acc[co][1] = a1v;
    }
  }
#pragma unroll
  for (int co = 0; co < 16; ++co) {
    int c = coT * 16 + co;
    float bias = st[1792 + c];
    float v0 = bias + acc[co][0];
    float v1 = bias + acc[co][1];
    size_t base = (size_t)b * 65536 + (size_t)c * 1024 + h * 32 + col0;
    if (MODE == 0) {
      outp[base] = v0; outp[base + 1] = v1;
    } else if (MODE == 1) {
      float cmv = st[1856 + c];
      const float* np_ = aux + (size_t)b * 65536 + (size_t)c * 1024;
      int y0 = h > 0 ? h - 1 : 0, y1 = h < 31 ? h + 1 : 31;
      float s0 = 0.f, s1 = 0.f;
      for (int y = y0; y <= y1; ++y) {
        float r[4];
#pragma unroll
        for (int j = 0; j < 4; ++j) {
          int xc = col0 - 1 + j;
          r[j] = ((unsigned)xc < 32u) ? np_[y * 32 + xc] : 0.f;
        }
        s0 += r[0] + r[1] + r[2];
        s1 += r[1] + r[2] + r[3];
      }
      float ny = (float)(y1 - y0 + 1);
      float d0 = ny * (col0 == 0 ? 2.f : 3.f);
      float d1 = ny * (col0 + 1 == 31 ? 2.f : 3.f);
      outp[base] = v0 + (s0 / d0) * cmv;
      outp[base + 1] = v1 + (s1 / d1) * cmv;
    } else if (MODE == 2) {
      float cmv = st[1856 + c];
      outp[base] = v0 + aux[base] * cmv;
      outp[base + 1] = v1 + aux[base + 1] * cmv;
    } else {
      outp[base] += v0;
      outp[base + 1] += v1;
    }
  }
}

extern "C" void kernel_launch(void* const* d_in, const int* in_sizes, int n_in,
                              void* d_out, int out_size, void* d_ws, size_t ws_size,
                              hipStream_t stream) {
  const float* x  = (const float*)d_in[0];
  const float* a1 = (const float*)d_in[1];
  const float* a2 = (const float*)d_in[2];
  const float* W1[4] = {(const float*)d_in[3], (const float*)d_in[5],
                        (const float*)d_in[7], (const float*)d_in[9]};
  const float* W2[4] = {(const float*)d_in[4], (const float*)d_in[6],
                        (const float*)d_in[8], (const float*)d_in[10]};
  float* out = (float*)d_out;
  float* wsf = (float*)d_ws;
  float* n1 = wsf;                 // 16 MB
  float* n2 = wsf + 4194304;       // 16 MB
  float* t  = wsf + 8388608;       // 16 MB
  float* st = wsf + 12582912;      // stats/coeffs (2048 floats)
  float* wE = wsf + 12584960;      // folded conv2 weights (36864 floats)

  prep_cm_k<<<1, 64, 0, stream>>>(a1, a2, st);

  dim3 gA(4, 4, 64), gC(4, 16, 64), gE(4, 4, 64);

  auto norconv = [&](const float* xin, const float* w1, const float* w2) {
    hipMemsetAsync(st, 0, 1152 * sizeof(float), stream);
    convA_k<<<gA, 128, 0, stream>>>(xin, w1, t, st);
    finalizeA_k<<<1, 64, 0, stream>>>(a1, st);
    convC_k<<<gC, 128, 0, stream>>>(t, st, w2);
    finalizeC_k<<<1, 64, 0, stream>>>(a2, st);
    prepE_k<<<64, 64, 0, stream>>>(w2, st, wE);
  };

  // n1 = nor_conv(inputs, W1_0, W2_0)
  norconv(x, W1[0], W2[0]);
  convE_k<0><<<gE, 128, 0, stream>>>(t, st, wE, n1, nullptr);
  // n2 = nor_conv(inputs, W1_1, W2_1) + avgpool3(n1)*cm
  norconv(x, W1[1], W2[1]);
  convE_k<1><<<gE, 128, 0, stream>>>(t, st, wE, n2, n1);
  // out = inputs*cm + nor_conv(n1, W1_4, W2_4)
  norconv(n1, W1[2], W2[2]);
  convE_k<2><<<gE, 128, 0, stream>>>(t, st, wE, out, x);
  // out += nor_conv(n2, W1_5, W2_5)
  norconv(n2, W1[3], W2[3]);
  convE_k<3><<<gE, 128, 0, stream>>>(t, st, wE, out, nullptr);
}

// Round 3
// 931.609 us; speedup vs baseline: 4.1775x; 4.0659x over previous
//
#include <hip/hip_runtime.h>

#define EPS 1e-5f
#define NRED 65536.0f   // B*H*W = 64*32*32

typedef short bf16x8 __attribute__((ext_vector_type(8)));
typedef float f32x4 __attribute__((ext_vector_type(4)));
typedef unsigned short u16;

__device__ __forceinline__ u16 f2bf(float x) {  // RNE f32->bf16
  union { float f; unsigned u; } v; v.f = x;
  unsigned r = v.u + 0x7FFF + ((v.u >> 16) & 1);
  return (u16)(r >> 16);
}
__device__ __forceinline__ float bf2f(u16 h) {
  union { unsigned u; float f; } v; v.u = ((unsigned)h) << 16;
  return v.f;
}

// ---------------- stats region per norconv e (floats, at stE) ----------------
// [0,64) sum1 | [64,128) sumsq1 | [128,640) sum2[k][c] | [640,1152) sumsq2[k][c]
// [1792,1856) bias2[c].  Global: st[8192..8256) = cm[c].

__global__ void prep_cm_k(const float* __restrict__ a1, const float* __restrict__ a2,
                          float* __restrict__ st) {
  int c = threadIdx.x, g = c >> 3;
  float m1 = 0.f, m2 = 0.f;
  for (int i = g; i < 8; ++i) { m1 += a1[i]; m2 += a2[i]; }
  st[8192 + c] = m1 * m2;
}

// wT1[e][tap][co][ci] bf16 from W1 (OIHW)
__global__ void pack_wT1_k(const float* __restrict__ w0, const float* __restrict__ w1,
                           const float* __restrict__ w2, const float* __restrict__ w3,
                           u16* __restrict__ wT1) {
  int e = blockIdx.x / 9, tap = blockIdx.x % 9;
  const float* w = e == 0 ? w0 : e == 1 ? w1 : e == 2 ? w2 : w3;
  u16* dst = wT1 + e * 36864 + tap * 4096;
  for (int idx = threadIdx.x; idx < 4096; idx += 256) {
    int co = idx >> 6, ci = idx & 63;
    dst[idx] = f2bf(w[(co * 64 + ci) * 9 + tap]);
  }
}

// wG[e][g][chunk][quad][co][cig] bf16, zero where tap=chunk*4+quad > 8
__global__ void pack_wG_k(const float* __restrict__ w0, const float* __restrict__ w1,
                          const float* __restrict__ w2, const float* __restrict__ w3,
                          u16* __restrict__ wG) {
  int e = blockIdx.y;
  const float* w = e == 0 ? w0 : e == 1 ? w1 : e == 2 ? w2 : w3;
  int bx = blockIdx.x;              // = g*12 + ch*4 + q
  int q = bx & 3, ch = (bx >> 2) % 3, g = bx / 12;
  int tap = ch * 4 + q;
  u16* dst = wG + e * 49152 + bx * 512;
  for (int idx = threadIdx.x; idx < 512; idx += 256) {
    int co = idx >> 3, cig = idx & 7;
    float v = (tap <= 8) ? w[(co * 64 + g * 8 + cig) * 9 + tap] : 0.f;
    dst[idx] = f2bf(v);
  }
}

// ---------------- convA: t = conv3x3(relu(src), W1) bf16 + fused stats --------
// grid (16 rowpairs, 64 B), block 256 = 4 waves; wave = 16-pixel tile, all 64 co.
__global__ __launch_bounds__(256) void convA_k(const float* __restrict__ src,
                                               const u16* __restrict__ wT,
                                               u16* __restrict__ t,
                                               float* __restrict__ st) {
  __shared__ __align__(16) u16 sh[136 * 72];
  __shared__ float sA[64], qA[64];
  const int tid = threadIdx.x;
  const int b = blockIdx.y, r0 = blockIdx.x * 2;
  if (tid < 64) { sA[tid] = 0.f; qA[tid] = 0.f; }
  const float* xb = src + (size_t)b * 65536;
  for (int idx = tid; idx < 8704; idx += 256) {
    int ci = idx / 136, p = idx - ci * 136;
    int pr = p / 34, pc = p - pr * 34;
    int r = r0 + pr - 1, c = pc - 1;
    float v = 0.f;
    if ((unsigned)r < 32u && (unsigned)c < 32u) v = xb[ci * 1024 + r * 32 + c];
    sh[p * 72 + ci] = f2bf(fmaxf(v, 0.f));
  }
  __syncthreads();
  const int lane = tid & 63, w = tid >> 6;
  const int ln = lane & 15, quad = lane >> 4;
  const int tr = w >> 1, colbase = (w & 1) * 16;
  const int c0 = colbase + ln;
  f32x4 acc[4];
#pragma unroll
  for (int mt = 0; mt < 4; ++mt) acc[mt] = (f32x4){0.f, 0.f, 0.f, 0.f};
#pragma unroll 1
  for (int tap = 0; tap < 9; ++tap) {
    int P = (tr + tap / 3) * 34 + c0 + tap % 3;
#pragma unroll
    for (int half = 0; half < 2; ++half) {
      bf16x8 bx = *(const bf16x8*)&sh[P * 72 + half * 32 + quad * 8];
#pragma unroll
      for (int mt = 0; mt < 4; ++mt) {
        bf16x8 aw = *(const bf16x8*)&wT[(tap * 64 + mt * 16 + ln) * 64 + half * 32 + quad * 8];
        acc[mt] = __builtin_amdgcn_mfma_f32_16x16x32_bf16(aw, bx, acc[mt], 0, 0, 0);
      }
    }
  }
  const int prow = r0 + tr;
  u16* tb = t + (size_t)b * 65536;
#pragma unroll
  for (int mt = 0; mt < 4; ++mt) {
#pragma unroll
    for (int r = 0; r < 4; ++r) {
      int co = mt * 16 + quad * 4 + r;
      float v = acc[mt][r];
      tb[co * 1024 + prow * 32 + c0] = f2bf(v);
      float s = v, q = v * v;
      s += __shfl_xor(s, 1); q += __shfl_xor(q, 1);
      s += __shfl_xor(s, 2); q += __shfl_xor(q, 2);
      s += __shfl_xor(s, 4); q += __shfl_xor(q, 4);
      s += __shfl_xor(s, 8); q += __shfl_xor(q, 8);
      if (ln == 0) { atomicAdd(&sA[co], s); atomicAdd(&qA[co], q); }
    }
  }
  __syncthreads();
  if (tid < 64) { atomicAdd(&st[tid], sA[tid]); atomicAdd(&st[64 + tid], qA[tid]); }
}

// ---------------- convC: per-group prefix stats of conv2 ---------------------
// grid (16,64), block 512 = 8 waves; wave = (pixel tile w&3, co-half w>>2).
__global__ __launch_bounds__(512) void convC_k(const u16* __restrict__ t,
                                               float* __restrict__ st,
                                               const u16* __restrict__ wG,
                                               const float* __restrict__ a1) {
  __shared__ __align__(16) u16 sh[136 * 72];
  __shared__ float s1L[64], b1L[64];
  __shared__ float sC[512], qC[512];
  const int tid = threadIdx.x;
  const int b = blockIdx.y, r0 = blockIdx.x * 2;
  if (tid < 64) {  // finalizeA per block
    int c = tid, g = c >> 3;
    float m = 0.f;
    for (int i = g; i < 8; ++i) m += a1[i];
    float mu = st[c] * (1.f / NRED);
    float var = st[64 + c] * (1.f / NRED) - mu * mu;
    float rr = rsqrtf(var + EPS);
    s1L[c] = rr * m; b1L[c] = -mu * rr * m;
  }
  sC[tid] = 0.f; qC[tid] = 0.f;
  __syncthreads();
  const u16* tb = t + (size_t)b * 65536;
  for (int idx = tid; idx < 8704; idx += 512) {
    int ci = idx / 136, p = idx - ci * 136;
    int pr = p / 34, pc = p - pr * 34;
    int r = r0 + pr - 1, c = pc - 1;
    float v = 0.f;
    if ((unsigned)r < 32u && (unsigned)c < 32u)
      v = bf2f(tb[ci * 1024 + r * 32 + c]) * s1L[ci] + b1L[ci];
    sh[p * 72 + ci] = f2bf(v);
  }
  __syncthreads();
  const int lane = tid & 63, w = tid >> 6;
  const int ln = lane & 15, quad = lane >> 4;
  const int nt = w & 3, ch2 = w >> 2;
  const int tr = nt >> 1, colbase = (nt & 1) * 16;
  const int c0 = colbase + ln;
  int Poff[3];
#pragma unroll
  for (int ch = 0; ch < 3; ++ch) {
    int tp = ch * 4 + quad; if (tp > 8) tp = 8;
    Poff[ch] = (tp / 3) * 34 + tp % 3;
  }
  f32x4 acc[8][2];
#pragma unroll
  for (int g = 0; g < 8; ++g)
#pragma unroll
    for (int m = 0; m < 2; ++m) acc[g][m] = (f32x4){0.f, 0.f, 0.f, 0.f};
#pragma unroll
  for (int g = 0; g < 8; ++g) {
#pragma unroll
    for (int ch = 0; ch < 3; ++ch) {
      bf16x8 bx = *(const bf16x8*)&sh[(tr * 34 + c0 + Poff[ch]) * 72 + g * 8];
#pragma unroll
      for (int mtl = 0; mtl < 2; ++mtl) {
        bf16x8 aw = *(const bf16x8*)&wG[((g * 12 + ch * 4 + quad) * 64 + ch2 * 32 + mtl * 16 + ln) * 8];
        acc[g][mtl] = __builtin_amdgcn_mfma_f32_16x16x32_bf16(aw, bx, acc[g][mtl], 0, 0, 0);
      }
    }
  }
  // prefix over groups + per-(k,co) sum/sumsq
  f32x4 P[2];
  P[0] = (f32x4){0.f, 0.f, 0.f, 0.f};
  P[1] = (f32x4){0.f, 0.f, 0.f, 0.f};
#pragma unroll
  for (int k = 0; k < 8; ++k) {
    P[0] += acc[k][0]; P[1] += acc[k][1];
#pragma unroll
    for (int mtl = 0; mtl < 2; ++mtl) {
#pragma unroll
      for (int r = 0; r < 4; ++r) {
        float s = P[mtl][r], q = s * s;
        s += __shfl_xor(s, 1); q += __shfl_xor(q, 1);
        s += __shfl_xor(s, 2); q += __shfl_xor(q, 2);
        s += __shfl_xor(s, 4); q += __shfl_xor(q, 4);
        s += __shfl_xor(s, 8); q += __shfl_xor(q, 8);
        if (ln == 0) {
          int co = ch2 * 32 + mtl * 16 + quad * 4 + r;
          atomicAdd(&sC[k * 64 + co], s);
          atomicAdd(&qC[k * 64 + co], q);
        }
      }
    }
  }
  __syncthreads();
  atomicAdd(&st[128 + tid], sC[tid]);
  atomicAdd(&st[640 + tid], qC[tid]);
}

// ---------------- prepE: finalizeC + fold g into conv2 weights ---------------
// grid(9 taps), block 256. wE[tap][co][ci] bf16; bias2 -> stE[1792+c].
__global__ void prepE_k(const float* __restrict__ w2, float* __restrict__ st,
                        const float* __restrict__ a2, u16* __restrict__ wE) {
  __shared__ float gL[512];
  int tid = threadIdx.x, tap = blockIdx.x;
  if (tid < 64) {
    int c = tid;
    float suf = 0.f, bias = 0.f;
    for (int k = 7; k >= 0; --k) {
      float mu = st[128 + k * 64 + c] * (1.f / NRED);
      float var = st[640 + k * 64 + c] * (1.f / NRED) - mu * mu;
      float rr = rsqrtf(var + EPS);
      bias -= a2[k] * mu * rr;
      suf += a2[k] * rr;
      gL[k * 64 + c] = suf;
    }
    st[1792 + c] = bias;  // all 9 blocks write bit-identical value
  }
  __syncthreads();
  for (int idx = tid; idx < 4096; idx += 256) {
    int co = idx >> 6, ci = idx & 63;
    wE[tap * 4096 + idx] = f2bf(w2[(co * 64 + ci) * 9 + tap] * gL[(ci >> 3) * 64 + co]);
  }
}

// ---------------- convE: mixed conv2 + epilogue ------------------------------
// MODE 0: n1 = v | 1: n2 = v + pooled(bf16, pre-scaled) | 2: out = v + x*cm | 3: out += v
template <int MODE>
__global__ __launch_bounds__(256) void convE_k(const u16* __restrict__ t,
                                               const float* __restrict__ st,
                                               const u16* __restrict__ wE,
                                               float* __restrict__ outp,
                                               const void* __restrict__ auxv,
                                               const float* __restrict__ a1,
                                               const float* __restrict__ cm) {
  __shared__ __align__(16) u16 sh[136 * 72];
  __shared__ float s1L[64], b1L[64];
  const int tid = threadIdx.x;
  const int b = blockIdx.y, r0 = blockIdx.x * 2;
  if (tid < 64) {
    int c = tid, g = c >> 3;
    float m = 0.f;
    for (int i = g; i < 8; ++i) m += a1[i];
    float mu = st[c] * (1.f / NRED);
    float var = st[64 + c] * (1.f / NRED) - mu * mu;
    float rr = rsqrtf(var + EPS);
    s1L[c] = rr * m; b1L[c] = -mu * rr * m;
  }
  __syncthreads();
  const u16* tb = t + (size_t)b * 65536;
  for (int idx = tid; idx < 8704; idx += 256) {
    int ci = idx / 136, p = idx - ci * 136;
    int pr = p / 34, pc = p - pr * 34;
    int r = r0 + pr - 1, c = pc - 1;
    float v = 0.f;
    if ((unsigned)r < 32u && (unsigned)c < 32u)
      v = bf2f(tb[ci * 1024 + r * 32 + c]) * s1L[ci] + b1L[ci];
    sh[p * 72 + ci] = f2bf(v);
  }
  __syncthreads();
  const int lane = tid & 63, w = tid >> 6;
  const int ln = lane & 15, quad = lane >> 4;
  const int tr = w >> 1, colbase = (w & 1) * 16;
  const int c0 = colbase + ln;
  f32x4 acc[4];
#pragma unroll
  for (int mt = 0; mt < 4; ++mt) acc[mt] = (f32x4){0.f, 0.f, 0.f, 0.f};
#pragma unroll 1
  for (int tap = 0; tap < 9; ++tap) {
    int P = (tr + tap / 3) * 34 + c0 + tap % 3;
#pragma unroll
    for (int half = 0; half < 2; ++half) {
      bf16x8 bx = *(const bf16x8*)&sh[P * 72 + half * 32 + quad * 8];
#pragma unroll
      for (int mt = 0; mt < 4; ++mt) {
        bf16x8 aw = *(const bf16x8*)&wE[(tap * 64 + mt * 16 + ln) * 64 + half * 32 + quad * 8];
        acc[mt] = __builtin_amdgcn_mfma_f32_16x16x32_bf16(aw, bx, acc[mt], 0, 0, 0);
      }
    }
  }
  const int prow = r0 + tr;
#pragma unroll
  for (int mt = 0; mt < 4; ++mt) {
#pragma unroll
    for (int r = 0; r < 4; ++r) {
      int co = mt * 16 + quad * 4 + r;
      float v = acc[mt][r] + st[1792 + co];
      size_t base = (size_t)b * 65536 + (size_t)co * 1024 + prow * 32 + c0;
      if (MODE == 0) {
        outp[base] = v;
      } else if (MODE == 1) {
        outp[base] = v + bf2f(((const u16*)auxv)[base]);
      } else if (MODE == 2) {
        outp[base] = v + ((const float*)auxv)[base] * cm[co];
      } else {
        outp[base] += v;
      }
    }
  }
}

// ---------------- avgpool3(n1)*cm -> bf16 ------------------------------------
__global__ __launch_bounds__(256) void pool_k(const float* __restrict__ n1,
                                              const float* __restrict__ cm,
                                              u16* __restrict__ pooled) {
  int idx = blockIdx.x * 256 + threadIdx.x;
  int cl = idx & 31, r = (idx >> 5) & 31, c = (idx >> 10) & 63, b = idx >> 16;
  const float* p = n1 + (size_t)(b * 64 + c) * 1024;
  int y0 = r > 0 ? r - 1 : 0, y1 = r < 31 ? r + 1 : 31;
  int x0 = cl > 0 ? cl - 1 : 0, x1 = cl < 31 ? cl + 1 : 31;
  float s = 0.f;
  for (int y = y0; y <= y1; ++y)
    for (int x = x0; x <= x1; ++x) s += p[y * 32 + x];
  pooled[idx] = f2bf(s / (float)((y1 - y0 + 1) * (x1 - x0 + 1)) * cm[c]);
}

extern "C" void kernel_launch(void* const* d_in, const int* in_sizes, int n_in,
                              void* d_out, int out_size, void* d_ws, size_t ws_size,
                              hipStream_t stream) {
  const float* x  = (const float*)d_in[0];
  const float* a1 = (const float*)d_in[1];
  const float* a2 = (const float*)d_in[2];
  const float* W1[4] = {(const float*)d_in[3], (const float*)d_in[5],
                        (const float*)d_in[7], (const float*)d_in[9]};
  const float* W2[4] = {(const float*)d_in[4], (const float*)d_in[6],
                        (const float*)d_in[8], (const float*)d_in[10]};
  float* out = (float*)d_out;
  char* ws = (char*)d_ws;
  float* n1     = (float*)ws;                       // 16 MB
  float* n2     = (float*)(ws + (16ull << 20));     // 16 MB
  u16*   pooled = (u16*)  (ws + (32ull << 20));     // 8 MB
  u16*   t      = (u16*)  (ws + (40ull << 20));     // 8 MB
  float* st     = (float*)(ws + (48ull << 20));     // 8256 floats
  u16*   wT1    = (u16*)  (ws + (48ull << 20) + 33024);
  u16*   wG     = wT1 + 4 * 36864;
  u16*   wE     = wG + 4 * 49152;
  const float* cm = st + 8192;

  hipMemsetAsync(st, 0, 8256 * sizeof(float), stream);
  prep_cm_k<<<1, 64, 0, stream>>>(a1, a2, st);
  pack_wT1_k<<<36, 256, 0, stream>>>(W1[0], W1[1], W1[2], W1[3], wT1);
  pack_wG_k<<<dim3(96, 4), 256, 0, stream>>>(W2[0], W2[1], W2[2], W2[3], wG);

  dim3 gs(16, 64);
  const float* ins[4] = {x, x, n1, n2};
  for (int e = 0; e < 4; ++e) {
    float* stE = st + e * 2048;
    convA_k<<<gs, 256, 0, stream>>>(ins[e], wT1 + e * 36864, t, stE);
    convC_k<<<gs, 512, 0, stream>>>(t, stE, wG + e * 49152, a1);
    prepE_k<<<9, 256, 0, stream>>>(W2[e], stE, a2, wE);
    if (e == 0) {
      convE_k<0><<<gs, 256, 0, stream>>>(t, stE, wE, n1, nullptr, a1, cm);
      pool_k<<<16384, 256, 0, stream>>>(n1, cm, pooled);
    } else if (e == 1) {
      convE_k<1><<<gs, 256, 0, stream>>>(t, stE, wE, n2, pooled, a1, cm);
    } else if (e == 2) {
      convE_k<2><<<gs, 256, 0, stream>>>(t, stE, wE, out, x, a1, cm);
    } else {
      convE_k<3><<<gs, 256, 0, stream>>>(t, stE, wE, out, nullptr, a1, cm);
    }
  }
}